// Round 15
// baseline (1718.685 us; speedup 1.0000x reference)
//
#include <hip/hip_runtime.h>
#include <math.h>

#define NN 512
#define BB 16
#define TOTAL (BB * NN * NN)   // 4,194,304 cells
#define EPS_F 1e-5f
#define DELTA_F 0.05f

#define HALO 8
#define TILE 80                 // register tile 80x80, valid center 64x64
#define OUT  64
#define PT   5                  // cells per thread per dim (80/16)
#define NT8  8                  // tiles per dim: 8*64 = 512, exact tiling
#define GUARD 16384

// bf16 helpers (storage only; all math in f32)
__device__ __forceinline__ float bf16_ld(unsigned short h) {
    return __uint_as_float((unsigned)h << 16);
}
__device__ __forceinline__ unsigned short bf16_st(float f) {
    unsigned b = __float_as_uint(f);
    return (unsigned short)((b + 0x7FFFu + ((b >> 16) & 1u)) >> 16);  // RNE
}

// 16-lane DPP shifts (proven R6/R7): boundary lanes -> 0, killed by ring cf=0
__device__ __forceinline__ float dpp_shr1(float x) {
    int r = __builtin_amdgcn_update_dpp(0, __float_as_int(x), 0x111, 0xf, 0xf, true);
    return __int_as_float(r);
}
__device__ __forceinline__ float dpp_shl1(float x) {
    int r = __builtin_amdgcn_update_dpp(0, __float_as_int(x), 0x101, 0xf, 0xf, true);
    return __int_as_float(r);
}

// ---------------------------------------------------------------------------
// Init (4 cells/thread, vectorized): u0(bf16) = dir ? bc : 0 ;
// cmask(u8) = fluid ; pre(bf16) = w_outer * [geom<=0.5] * (x·w_back + b) ;
// zero the 1024 sync flags (every call — replay-safe).
// ---------------------------------------------------------------------------
__global__ __launch_bounds__(256) void init_kernel(
    const float4* __restrict__ xm4,
    unsigned short* __restrict__ u,
    unsigned char* __restrict__ cmask,
    unsigned short* __restrict__ pre,
    int* __restrict__ flags,
    const float* __restrict__ w_back,
    const float* __restrict__ b_back)
{
    int g = blockIdx.x * 256 + threadIdx.x;      // 0 .. TOTAL/4-1
    if (g < NT8 * NT8 * BB) flags[g] = 0;

    int idx = g * 4;
    int j0 = idx & (NN - 1);
    int i  = (idx >> 9) & (NN - 1);
    float w0 = w_back[0], w1 = w_back[1], bb0 = b_back[0];
    float xs = (float)i * (1.0f / 511.0f);
    float dx = fminf(xs, 1.0f - xs);
    bool iedge = (i == 0) | (i == NN - 1);

    unsigned uw[2] = {0u, 0u};
    unsigned mw = 0u;
    unsigned pw[2] = {0u, 0u};
#pragma unroll
    for (int c = 0; c < 4; ++c) {
        float4 xm = xm4[idx + c];
        int j = j0 + c;
        bool dir = iedge | (j == 0) | (j == NN - 1) | (xm.z > 0.5f);
        unsigned us = bf16_st(dir ? xm.w : 0.0f);
        uw[c >> 1] |= us << ((c & 1) * 16);
        mw |= (dir ? 0u : 1u) << (c * 8);

        float rr = xm.x * w0 + xm.y * w1 + bb0;
        float ys = (float)j * (1.0f / 511.0f);
        float dd = fminf(dx, fminf(ys, 1.0f - ys));
        float ww = fminf(fmaxf(dd * (1.0f / DELTA_F), 0.0f), 1.0f);
        if (xm.z > 0.5f) ww = 0.0f;
        unsigned ps = bf16_st(ww * rr);
        pw[c >> 1] |= ps << ((c & 1) * 16);
    }
    *(uint2*)(u + idx)        = make_uint2(uw[0], uw[1]);
    *(unsigned*)(cmask + idx) = mw;
    *(uint2*)(pre + idx)      = make_uint2(pw[0], pw[1]);
}

// ---------------------------------------------------------------------------
// Persistent kernel: all 50 Jacobi iterations in ONE launch.
// 1024 blocks (8x8x16) = exactly 4/CU, guaranteed co-resident by
// __launch_bounds__(256,4) (VGPR<=128 -> 4 waves/SIMD) + 10.2 KB LDS.
// Per phase (8 iters): proven R6 register-tile core (LDS/DPP halo, 1
// barrier/iter). Between phases: publish 8-deep center frame with plain
// stores (double-buffered u_b/u_a), __threadfence + release-flag (agent);
// spin-wait (acquire, agent) on <=8 neighbors' flags; re-read 8-deep ring.
// Race-free: a buffer's frame cells are only overwritten at phase p+2 after
// all readers (self + 8 neighbors) advanced past phase p (flag ordering).
// Ring cells frozen (cf=0) annihilate garbage halo via fma; guarded OOB
// reads decode finite and cannot cross the frozen global-edge rows/cols.
// ---------------------------------------------------------------------------
__global__ __launch_bounds__(256, 4) void persist_kernel(
    unsigned short* u_a,
    unsigned short* u_b,
    const unsigned char* cmask,
    const unsigned short* pre,
    float* fout,
    int* flags,
    const float* logit,
    const float* y_mean,
    const float* y_std)
{
    __shared__ float xup[2][PT][256];
    __shared__ float xdn[2][PT][256];

    const int b   = blockIdx.z;
    const int ty  = blockIdx.y;
    const int tx  = blockIdx.x;
    const int oy  = ty * OUT;
    const int ox  = tx * OUT;
    const int tid = threadIdx.x;
    const int tr  = tid >> 4;
    const int tc  = tid & 15;
    const int R0  = tr * PT;
    const int C0  = tc * PT;
    const int slab = b * NN * NN;
    const int myflag = (b * NT8 + ty) * NT8 + tx;

    float u[PT][PT];
    float cf[PT][PT];

    // ---- setup: load 5x5 u + coeffs (guarded offsets; tile ring frozen) ----
#pragma unroll
    for (int r = 0; r < PT; ++r) {
        int tyy = R0 + r;
        int gy  = oy - HALO + tyy;
#pragma unroll
        for (int c = 0; c < PT; ++c) {
            int txx = C0 + c;
            int gx  = ox - HALO + txx;
            int off = slab + gy * NN + gx;     // may stray into guard: finite
            u[r][c] = bf16_ld(u_a[off]);
            unsigned m = cmask[off];
            bool ring = (tyy == 0) | (tyy == TILE - 1) | (txx == 0) | (txx == TILE - 1);
            cf[r][c] = (ring || m == 0u) ? 0.0f : 1.0f;
        }
    }

    const int tup = (tid >= 16)  ? tid - 16 : tid;
    const int tdn = (tid < 240)  ? tid + 16 : tid;

    auto iterate = [&](int iters) {
#pragma unroll 1
        for (int t = 0; t < iters; ++t) {
            const int pb = t & 1;
#pragma unroll
            for (int w = 0; w < PT; ++w) {
                xup[pb][w][tid] = u[0][w];
                xdn[pb][w][tid] = u[PT - 1][w];
            }
            float lsh[PT], rsh[PT];
#pragma unroll
            for (int r = 0; r < PT; ++r) {
                lsh[r] = dpp_shr1(u[r][PT - 1]);
                rsh[r] = dpp_shl1(u[r][0]);
            }
            __syncthreads();
            float th[PT], bh[PT];
#pragma unroll
            for (int w = 0; w < PT; ++w) {
                th[w] = xdn[pb][w][tup];
                bh[w] = xup[pb][w][tdn];
            }
            float prow[PT];
#pragma unroll
            for (int c = 0; c < PT; ++c) prow[c] = th[c];
#pragma unroll
            for (int r = 0; r < PT; ++r) {
                float orow[PT];
#pragma unroll
                for (int c = 0; c < PT; ++c) orow[c] = u[r][c];
#pragma unroll
                for (int c = 0; c < PT; ++c) {
                    float up = prow[c];
                    float dn = (r < PT - 1) ? u[r + 1][c] : bh[c];
                    float lf = (c > 0)      ? orow[c - 1] : lsh[r];
                    float rt = (c < PT - 1) ? orow[c + 1] : rsh[r];
                    float s  = (up + dn) + (lf + rt);
                    float od = orow[c];
                    float tq = __builtin_fmaf(0.25f, s, -od);
                    u[r][c]  = __builtin_fmaf(cf[r][c], tq, od);
                }
#pragma unroll
                for (int c = 0; c < PT; ++c) prow[c] = orow[c];
            }
        }
    };

    // ---- 6 phases x 8 iters with neighbor-flag exchange ----
#pragma unroll 1
    for (int p = 0; p < 6; ++p) {
        iterate(8);
        unsigned short* buf = (p & 1) ? u_a : u_b;
        // publish my center's 8-deep frame (plain stores)
#pragma unroll
        for (int r = 0; r < PT; ++r) {
            int tyy = R0 + r;
#pragma unroll
            for (int c = 0; c < PT; ++c) {
                int txx = C0 + c;
                bool center = (tyy >= HALO) & (tyy < TILE - HALO) &
                              (txx >= HALO) & (txx < TILE - HALO);
                bool frame  = center & ((tyy < 2*HALO) | (tyy >= TILE - 2*HALO) |
                                        (txx < 2*HALO) | (txx >= TILE - 2*HALO));
                if (frame)
                    buf[slab + (oy - HALO + tyy) * NN + (ox - HALO + txx)] =
                        bf16_st(u[r][c]);
            }
        }
        __threadfence();          // my stores globally visible (L2 writeback)
        __syncthreads();          // whole block done publishing
        if (tid == 0)
            __hip_atomic_store(&flags[myflag], p + 1, __ATOMIC_RELEASE,
                               __HIP_MEMORY_SCOPE_AGENT);
        // wait for <=8 neighbors to publish phase p
        if (tid < 8) {
            const int dy[8] = {-1,-1,-1, 0, 0, 1, 1, 1};
            const int dx[8] = {-1, 0, 1,-1, 1,-1, 0, 1};
            int nty = ty + dy[tid], ntx = tx + dx[tid];
            if ((unsigned)nty < (unsigned)NT8 && (unsigned)ntx < (unsigned)NT8) {
                const int nf = (b * NT8 + nty) * NT8 + ntx;
                long guard_ctr = 0;
                while (__hip_atomic_load(&flags[nf], __ATOMIC_ACQUIRE,
                                         __HIP_MEMORY_SCOPE_AGENT) < p + 1) {
                    __builtin_amdgcn_s_sleep(1);
                    if (++guard_ctr > (1L << 28)) break;   // bail: no hang
                }
            }
        }
        __syncthreads();
        __threadfence();          // invalidate stale cached lines before reads
        // refresh my 8-deep ring from neighbors' frames
#pragma unroll
        for (int r = 0; r < PT; ++r) {
            int tyy = R0 + r;
#pragma unroll
            for (int c = 0; c < PT; ++c) {
                int txx = C0 + c;
                if ((tyy < HALO) | (tyy >= TILE - HALO) |
                    (txx < HALO) | (txx >= TILE - HALO)) {
                    int off = slab + (oy - HALO + tyy) * NN + (ox - HALO + txx);
                    u[r][c] = bf16_ld(buf[off]);   // OOB -> guarded finite
                }
            }
        }
        __syncthreads();
    }

    iterate(2);   // total 50

    // ---- fused epilogue: out = (u-ym)/ysd + rs*pre  (center 64x64) ----
    {
        float rs  = 0.25f / (1.0f + expf(-logit[0]));
        float ym  = y_mean[0];
        float inv = 1.0f / (y_std[0] + EPS_F);
        const unsigned short* pg = pre + slab;
        float* og = fout + slab;
#pragma unroll
        for (int r = 0; r < PT; ++r) {
            int cy = R0 + r - HALO;
#pragma unroll
            for (int c = 0; c < PT; ++c) {
                int cx = C0 + c - HALO;
                if ((unsigned)cy < (unsigned)OUT && (unsigned)cx < (unsigned)OUT) {
                    int gi = oy + cy, gj = ox + cx;
                    float e = (u[r][c] - ym) * inv;
                    float pp = bf16_ld(pg[gi * NN + gj]);
                    og[gi * NN + gj] = __builtin_fmaf(rs, pp, e);
                }
            }
        }
    }
}

// ---------------------------------------------------------------------------
extern "C" void kernel_launch(void* const* d_in, const int* in_sizes, int n_in,
                              void* d_out, int out_size, void* d_ws, size_t ws_size,
                              hipStream_t stream)
{
    const float* x_mix  = (const float*)d_in[0];
    const float* w_back = (const float*)d_in[1];
    const float* b_back = (const float*)d_in[2];
    const float* logit  = (const float*)d_in[3];
    const float* y_mean = (const float*)d_in[4];
    const float* y_std  = (const float*)d_in[5];

    float* out = (float*)d_out;

    // Workspace: [GUARD][u_a 2B][cmask 1B][u_b 2B][pre 2B][flags 4KB]
    // Halo reads may stray <= ~8.3 KB past either end of u_a/cmask/u_b; all
    // such accesses land in adjacent defined regions or the guard (finite).
    char* ws = (char*)d_ws;
    unsigned short* u_a   = (unsigned short*)(ws + GUARD);
    unsigned char*  cmask = (unsigned char*) (ws + GUARD + (size_t)TOTAL * 2);
    unsigned short* u_b   = (unsigned short*)(ws + GUARD + (size_t)TOTAL * 3);
    unsigned short* pre   = (unsigned short*)(ws + GUARD + (size_t)TOTAL * 5);
    int*            flags = (int*)           (ws + GUARD + (size_t)TOTAL * 7);

    init_kernel<<<TOTAL / 4 / 256, 256, 0, stream>>>(
        (const float4*)x_mix, u_a, cmask, pre, flags, w_back, b_back);

    persist_kernel<<<dim3(NT8, NT8, BB), 256, 0, stream>>>(
        u_a, u_b, cmask, pre, out, flags, logit, y_mean, y_std);
}

// Round 16
// 144.813 us; speedup vs baseline: 11.8683x; 11.8683x over previous
//
#include <hip/hip_runtime.h>
#include <math.h>

#define NN 512
#define BB 16
#define TOTAL (BB * NN * NN)   // 4,194,304 cells
#define EPS_F 1e-5f
#define DELTA_F 0.05f

#define HALO 10
#define TILE 80                 // register tile 80x80, valid center 60x60
#define OUT  60
#define PT   5                  // cells per thread per dim (80/16)
#define NT   9                  // ceil(512/60): 9 tiles per dim (overlapped)
#define GUARD 16384             // worst halo stray = 10 rows ~ 10.3 KB < GUARD

// bf16 helpers (storage only; all math in f32)
__device__ __forceinline__ float bf16_ld(unsigned short h) {
    return __uint_as_float((unsigned)h << 16);
}
__device__ __forceinline__ unsigned short bf16_st(float f) {
    unsigned b = __float_as_uint(f);
    return (unsigned short)((b + 0x7FFFu + ((b >> 16) & 1u)) >> 16);  // RNE
}

// 16-lane DPP shifts: boundary lanes -> 0, annihilated by ring cf=0
__device__ __forceinline__ float dpp_shr1(float x) {
    int r = __builtin_amdgcn_update_dpp(0, __float_as_int(x), 0x111, 0xf, 0xf, true);
    return __int_as_float(r);
}
__device__ __forceinline__ float dpp_shl1(float x) {
    int r = __builtin_amdgcn_update_dpp(0, __float_as_int(x), 0x101, 0xf, 0xf, true);
    return __int_as_float(r);
}

// ---------------------------------------------------------------------------
// Init (4 cells/thread, vectorized): u0(bf16) = dir ? bc : 0 ;
// cmask(u8) = fluid ; pre(bf16) = w_outer * [geom<=0.5] * (x·w_back + b)
// ---------------------------------------------------------------------------
__global__ __launch_bounds__(256) void init_kernel(
    const float4* __restrict__ xm4,
    unsigned short* __restrict__ u,
    unsigned char* __restrict__ cmask,
    unsigned short* __restrict__ pre,
    const float* __restrict__ w_back,
    const float* __restrict__ b_back)
{
    int g = blockIdx.x * 256 + threadIdx.x;      // 0 .. TOTAL/4-1
    int idx = g * 4;
    int j0 = idx & (NN - 1);
    int i  = (idx >> 9) & (NN - 1);
    float w0 = w_back[0], w1 = w_back[1], bb0 = b_back[0];
    float xs = (float)i * (1.0f / 511.0f);
    float dx = fminf(xs, 1.0f - xs);
    bool iedge = (i == 0) | (i == NN - 1);

    unsigned uw[2] = {0u, 0u};
    unsigned mw = 0u;
    unsigned pw[2] = {0u, 0u};
#pragma unroll
    for (int c = 0; c < 4; ++c) {
        float4 xm = xm4[idx + c];
        int j = j0 + c;
        bool dir = iedge | (j == 0) | (j == NN - 1) | (xm.z > 0.5f);
        unsigned us = bf16_st(dir ? xm.w : 0.0f);
        uw[c >> 1] |= us << ((c & 1) * 16);
        mw |= (dir ? 0u : 1u) << (c * 8);

        float rr = xm.x * w0 + xm.y * w1 + bb0;
        float ys = (float)j * (1.0f / 511.0f);
        float dd = fminf(dx, fminf(ys, 1.0f - ys));
        float ww = fminf(fmaxf(dd * (1.0f / DELTA_F), 0.0f), 1.0f);
        if (xm.z > 0.5f) ww = 0.0f;
        unsigned ps = bf16_st(ww * rr);
        pw[c >> 1] |= ps << ((c & 1) * 16);
    }
    *(uint2*)(u + idx)        = make_uint2(uw[0], uw[1]);
    *(unsigned*)(cmask + idx) = mw;
    *(uint2*)(pre + idx)      = make_uint2(pw[0], pw[1]);
}

// ---------------------------------------------------------------------------
// Register-tile temporal-blocked stencil: 10 Jacobi iters per launch.
// 16x16 threads own an 80x80 tile (60x60 output, halo 10 >= ITERS).
// u + fluid coeffs in VGPRs; vertical halo via transposed conflict-free LDS
// (double-buffered, 1 barrier/iter); horizontal halo via DPP lane shifts.
// Ring cells frozen (cf=0) annihilate garbage halo values via fma; guarded
// OOB reads decode finite and cannot cross the frozen global-edge rows/cols.
// Overlapping tiles (OUT=60, min-clamped origins) write identical values.
// ---------------------------------------------------------------------------
template<int ITERS, bool FINAL>
__global__ __launch_bounds__(256, 5) void stencil_kernel(
    const unsigned short* __restrict__ uin,
    unsigned short* __restrict__ uout,      // bf16 dest (non-final)
    float* __restrict__ fout,               // f32 dest (final)
    const unsigned char* __restrict__ cmask,
    const unsigned short* __restrict__ pre,
    const float* __restrict__ logit,
    const float* __restrict__ y_mean,
    const float* __restrict__ y_std)
{
    __shared__ float xup[2][PT][256];   // thread row 0 (for tr-1)
    __shared__ float xdn[2][PT][256];   // thread row PT-1 (for tr+1)

    const int b   = blockIdx.z;
    const int oy  = min((int)blockIdx.y * OUT, NN - OUT);
    const int ox  = min((int)blockIdx.x * OUT, NN - OUT);
    const int tid = threadIdx.x;
    const int tr  = tid >> 4;
    const int tc  = tid & 15;
    const int R0  = tr * PT;
    const int C0  = tc * PT;

    const int slab = b * NN * NN;
    const unsigned short* ub = uin + slab;
    const unsigned char*  cb = cmask + slab;

    float u[PT][PT];
    float cf[PT][PT];   // 1.0 = fluid (update), 0.0 = Dirichlet/frozen

    // ---- setup: load 5x5 u + coeffs (guarded offsets; tile ring frozen) ----
#pragma unroll
    for (int r = 0; r < PT; ++r) {
        int ty = R0 + r;
        int gy = oy - HALO + ty;
#pragma unroll
        for (int c = 0; c < PT; ++c) {
            int tx  = C0 + c;
            int gx  = ox - HALO + tx;
            int off = gy * NN + gx;            // may stray into guard: finite
            u[r][c] = bf16_ld(ub[off]);
            unsigned m = cb[off];
            bool ring = (ty == 0) | (ty == TILE - 1) | (tx == 0) | (tx == TILE - 1);
            cf[r][c] = (ring || m == 0u) ? 0.0f : 1.0f;
        }
    }

    const int tup = (tid >= 16)  ? tid - 16 : tid;   // clamped neighbor indices
    const int tdn = (tid < 240)  ? tid + 16 : tid;

    // ---- ITERS fused Jacobi iterations, all in registers ----
#pragma unroll 1
    for (int t = 0; t < ITERS; ++t) {
        const int pb = t & 1;
#pragma unroll
        for (int w = 0; w < PT; ++w) {
            xup[pb][w][tid] = u[0][w];
            xdn[pb][w][tid] = u[PT - 1][w];
        }
        float lsh[PT], rsh[PT];
#pragma unroll
        for (int r = 0; r < PT; ++r) {
            lsh[r] = dpp_shr1(u[r][PT - 1]);
            rsh[r] = dpp_shl1(u[r][0]);
        }
        __syncthreads();
        float th[PT], bh[PT];
#pragma unroll
        for (int w = 0; w < PT; ++w) {
            th[w] = xdn[pb][w][tup];   // garbage for tr==0: ring cf=0 kills it
            bh[w] = xup[pb][w][tdn];   // garbage for tr==15: ring cf=0 kills it
        }
        float prow[PT];
#pragma unroll
        for (int c = 0; c < PT; ++c) prow[c] = th[c];
#pragma unroll
        for (int r = 0; r < PT; ++r) {
            float orow[PT];
#pragma unroll
            for (int c = 0; c < PT; ++c) orow[c] = u[r][c];
#pragma unroll
            for (int c = 0; c < PT; ++c) {
                float up = prow[c];
                float dn = (r < PT - 1) ? u[r + 1][c] : bh[c];
                float lf = (c > 0)      ? orow[c - 1] : lsh[r];
                float rt = (c < PT - 1) ? orow[c + 1] : rsh[r];
                float s  = (up + dn) + (lf + rt);
                float od = orow[c];
                float tq = __builtin_fmaf(0.25f, s, -od);
                u[r][c]  = __builtin_fmaf(cf[r][c], tq, od);
            }
#pragma unroll
            for (int c = 0; c < PT; ++c) prow[c] = orow[c];
        }
    }

    // ---- store center 60x60 ----
    if (!FINAL) {
        unsigned short* og = uout + slab;
#pragma unroll
        for (int r = 0; r < PT; ++r) {
            int cy = R0 + r - HALO;
#pragma unroll
            for (int c = 0; c < PT; ++c) {
                int cx = C0 + c - HALO;
                if ((unsigned)cy < (unsigned)OUT && (unsigned)cx < (unsigned)OUT)
                    og[(oy + cy) * NN + (ox + cx)] = bf16_st(u[r][c]);
            }
        }
    } else {
        float* og = fout + slab;
        const unsigned short* pg = pre + slab;
        float rs  = 0.25f / (1.0f + expf(-logit[0]));
        float ym  = y_mean[0];
        float inv = 1.0f / (y_std[0] + EPS_F);
#pragma unroll
        for (int r = 0; r < PT; ++r) {
            int cy = R0 + r - HALO;
#pragma unroll
            for (int c = 0; c < PT; ++c) {
                int cx = C0 + c - HALO;
                if ((unsigned)cy < (unsigned)OUT && (unsigned)cx < (unsigned)OUT) {
                    int gi = oy + cy, gj = ox + cx;
                    float e = (u[r][c] - ym) * inv;
                    float p = bf16_ld(pg[gi * NN + gj]);
                    og[gi * NN + gj] = __builtin_fmaf(rs, p, e);
                }
            }
        }
    }
}

// ---------------------------------------------------------------------------
extern "C" void kernel_launch(void* const* d_in, const int* in_sizes, int n_in,
                              void* d_out, int out_size, void* d_ws, size_t ws_size,
                              hipStream_t stream)
{
    const float* x_mix  = (const float*)d_in[0];
    const float* w_back = (const float*)d_in[1];
    const float* b_back = (const float*)d_in[2];
    const float* logit  = (const float*)d_in[3];
    const float* y_mean = (const float*)d_in[4];
    const float* y_std  = (const float*)d_in[5];

    float* out = (float*)d_out;

    // Workspace: [GUARD][u_a 2B][cmask 1B][u_b 2B][pre 2B] — halo reads may
    // stray up to ~10.3 KB past either end of u_a/cmask/u_b; every such
    // access lands in an adjacent defined region or the guard (finite bf16).
    char* ws = (char*)d_ws;
    unsigned short* u_a   = (unsigned short*)(ws + GUARD);
    unsigned char*  cmask = (unsigned char*) (ws + GUARD + (size_t)TOTAL * 2);
    unsigned short* u_b   = (unsigned short*)(ws + GUARD + (size_t)TOTAL * 3);
    unsigned short* pre   = (unsigned short*)(ws + GUARD + (size_t)TOTAL * 5);

    init_kernel<<<TOTAL / 4 / 256, 256, 0, stream>>>(
        (const float4*)x_mix, u_a, cmask, pre, w_back, b_back);

    // 50 iters = 5 launches x 10 (last fused with epilogue).
    // Chain: a->b, b->a, a->b, b->a, then FINAL a->out? (4 swaps end in u_a)
    dim3 sgrid(NT, NT, BB);   // 9 x 9 x 16 = 1296 blocks (~5/CU, 1 sched wave)
    stencil_kernel<10, false><<<sgrid, 256, 0, stream>>>(u_a, u_b, out, cmask,
        pre, logit, y_mean, y_std);
    stencil_kernel<10, false><<<sgrid, 256, 0, stream>>>(u_b, u_a, out, cmask,
        pre, logit, y_mean, y_std);
    stencil_kernel<10, false><<<sgrid, 256, 0, stream>>>(u_a, u_b, out, cmask,
        pre, logit, y_mean, y_std);
    stencil_kernel<10, false><<<sgrid, 256, 0, stream>>>(u_b, u_a, out, cmask,
        pre, logit, y_mean, y_std);
    stencil_kernel<10, true><<<sgrid, 256, 0, stream>>>(u_a, u_b, out, cmask,
        pre, logit, y_mean, y_std);
}

// Round 17
// 128.447 us; speedup vs baseline: 13.3805x; 1.1274x over previous
//
#include <hip/hip_runtime.h>
#include <math.h>

#define NN 512
#define BB 16
#define TOTAL (BB * NN * NN)   // 4,194,304 cells
#define EPS_F 1e-5f
#define DELTA_F 0.05f

#define HALO 8
#define TILE_H 128              // tile rows (16 threads x 8)
#define TILE_W 64               // tile cols (16 threads x 4)
#define OUT_H  112              // valid center rows
#define OUT_W  48               // valid center cols
#define PTY 8
#define PTX 4
#define GUARD 16384             // halo stray <= ~8.3 KB

// bf16 helpers (storage only; all math in f32)
__device__ __forceinline__ float bf16_ld(unsigned short h) {
    return __uint_as_float((unsigned)h << 16);
}
__device__ __forceinline__ unsigned short bf16_st(float f) {
    unsigned b = __float_as_uint(f);
    return (unsigned short)((b + 0x7FFFu + ((b >> 16) & 1u)) >> 16);  // RNE
}

// 16-lane DPP shifts: boundary lanes -> 0, annihilated by ring cf=0
__device__ __forceinline__ float dpp_shr1(float x) {
    int r = __builtin_amdgcn_update_dpp(0, __float_as_int(x), 0x111, 0xf, 0xf, true);
    return __int_as_float(r);
}
__device__ __forceinline__ float dpp_shl1(float x) {
    int r = __builtin_amdgcn_update_dpp(0, __float_as_int(x), 0x101, 0xf, 0xf, true);
    return __int_as_float(r);
}

// ---------------------------------------------------------------------------
// Init (4 cells/thread, vectorized): u0(bf16) = dir ? bc : 0 ;
// cmask(u8) = fluid ; pre(bf16) = w_outer * [geom<=0.5] * (x·w_back + b)
// ---------------------------------------------------------------------------
__global__ __launch_bounds__(256) void init_kernel(
    const float4* __restrict__ xm4,
    unsigned short* __restrict__ u,
    unsigned char* __restrict__ cmask,
    unsigned short* __restrict__ pre,
    const float* __restrict__ w_back,
    const float* __restrict__ b_back)
{
    int g = blockIdx.x * 256 + threadIdx.x;      // 0 .. TOTAL/4-1
    int idx = g * 4;
    int j0 = idx & (NN - 1);
    int i  = (idx >> 9) & (NN - 1);
    float w0 = w_back[0], w1 = w_back[1], bb0 = b_back[0];
    float xs = (float)i * (1.0f / 511.0f);
    float dx = fminf(xs, 1.0f - xs);
    bool iedge = (i == 0) | (i == NN - 1);

    unsigned uw[2] = {0u, 0u};
    unsigned mw = 0u;
    unsigned pw[2] = {0u, 0u};
#pragma unroll
    for (int c = 0; c < 4; ++c) {
        float4 xm = xm4[idx + c];
        int j = j0 + c;
        bool dir = iedge | (j == 0) | (j == NN - 1) | (xm.z > 0.5f);
        unsigned us = bf16_st(dir ? xm.w : 0.0f);
        uw[c >> 1] |= us << ((c & 1) * 16);
        mw |= (dir ? 0u : 1u) << (c * 8);

        float rr = xm.x * w0 + xm.y * w1 + bb0;
        float ys = (float)j * (1.0f / 511.0f);
        float dd = fminf(dx, fminf(ys, 1.0f - ys));
        float ww = fminf(fmaxf(dd * (1.0f / DELTA_F), 0.0f), 1.0f);
        if (xm.z > 0.5f) ww = 0.0f;
        unsigned ps = bf16_st(ww * rr);
        pw[c >> 1] |= ps << ((c & 1) * 16);
    }
    *(uint2*)(u + idx)        = make_uint2(uw[0], uw[1]);
    *(unsigned*)(cmask + idx) = mw;
    *(uint2*)(pre + idx)      = make_uint2(pw[0], pw[1]);
}

// ---------------------------------------------------------------------------
// Tall register-tile stencil: 16x16 threads, each owns 8 rows x 4 cols of a
// 128x64 tile (112x48 center, halo 8 >= ITERS). Halo amplification 1.52
// (vs 1.89 at 64x64) — less state re-staged across the launch boundary.
// 7/8 of vertical neighbors in-register; band boundaries via transposed
// conflict-free LDS (publish rows 0 and 7 only; double-buffered, 1
// barrier/iter); horizontal via DPP16 lane shifts. Ring cells frozen (cf=0)
// annihilate garbage halo values via fma; guarded OOB reads decode finite
// and cannot cross the frozen global-edge rows/cols. Overlapping tiles
// (min-clamped origins) write identical values.
// ---------------------------------------------------------------------------
template<int ITERS, bool FINAL>
__global__ __launch_bounds__(256, 4) void stencil_kernel(
    const unsigned short* __restrict__ uin,
    unsigned short* __restrict__ uout,      // bf16 dest (non-final)
    float* __restrict__ fout,               // f32 dest (final)
    const unsigned char* __restrict__ cmask,
    const unsigned short* __restrict__ pre,
    const float* __restrict__ logit,
    const float* __restrict__ y_mean,
    const float* __restrict__ y_std)
{
    __shared__ float xup[2][PTX][256];   // each thread's row 0 (for tr-1)
    __shared__ float xdn[2][PTX][256];   // each thread's row 7 (for tr+1)

    const int b   = blockIdx.z;
    const int oy  = min((int)blockIdx.y * OUT_H, NN - OUT_H);
    const int ox  = min((int)blockIdx.x * OUT_W, NN - OUT_W);
    const int tid = threadIdx.x;
    const int tr  = tid >> 4;          // 0..15, owns 8 rows
    const int tc  = tid & 15;          // 0..15, owns 4 cols
    const int R0  = tr * PTY;
    const int C0  = tc * PTX;
    const int ty0 = oy - HALO;
    const int tx0 = ox - HALO;

    const int slab = b * NN * NN;
    const unsigned short* ub = uin + slab;
    const unsigned char*  cb = cmask + slab;

    float u[PTY][PTX];
    float cf[PTY][PTX];   // 1.0 = fluid (update), 0.0 = Dirichlet/frozen

    // ---- setup: per row one uint2(u16x4) + one uint(mask x4), guarded ----
#pragma unroll
    for (int r = 0; r < PTY; ++r) {
        int ty  = R0 + r;
        int off = (ty0 + ty) * NN + tx0 + C0;   // may stray into guard: finite
        uint2 v = *(const uint2*)(ub + off);
        unsigned mm = *(const unsigned*)(cb + off);
        unsigned uwv[2] = {v.x, v.y};
#pragma unroll
        for (int c = 0; c < PTX; ++c) {
            unsigned hw = (uwv[c >> 1] >> ((c & 1) * 16)) & 0xFFFFu;
            u[r][c] = __uint_as_float(hw << 16);
            unsigned m = (mm >> (c * 8)) & 0xFFu;
            int tx = C0 + c;
            bool ring = (ty == 0) | (ty == TILE_H - 1) | (tx == 0) | (tx == TILE_W - 1);
            cf[r][c] = (ring || m == 0u) ? 0.0f : 1.0f;
        }
    }

    const int tup = (tid >= 16)  ? tid - 16 : tid;   // clamped; garbage killed by ring
    const int tdn = (tid < 240)  ? tid + 16 : tid;

    // ---- ITERS fused Jacobi iterations, all in registers ----
#pragma unroll 1
    for (int t = 0; t < ITERS; ++t) {
        const int pb = t & 1;
#pragma unroll
        for (int w = 0; w < PTX; ++w) {
            xup[pb][w][tid] = u[0][w];
            xdn[pb][w][tid] = u[PTY - 1][w];
        }
        float lsh[PTY], rsh[PTY];
#pragma unroll
        for (int r = 0; r < PTY; ++r) {
            lsh[r] = dpp_shr1(u[r][PTX - 1]);
            rsh[r] = dpp_shl1(u[r][0]);
        }
        __syncthreads();
        float th[PTX], bh[PTX];
#pragma unroll
        for (int w = 0; w < PTX; ++w) {
            th[w] = xdn[pb][w][tup];   // garbage for tr==0: ring cf=0 kills it
            bh[w] = xup[pb][w][tdn];   // garbage for tr==15: ring cf=0 kills it
        }
        float prow[PTX];
#pragma unroll
        for (int c = 0; c < PTX; ++c) prow[c] = th[c];
#pragma unroll
        for (int r = 0; r < PTY; ++r) {
            float orow[PTX];
#pragma unroll
            for (int c = 0; c < PTX; ++c) orow[c] = u[r][c];
#pragma unroll
            for (int c = 0; c < PTX; ++c) {
                float up = prow[c];
                float dn = (r < PTY - 1) ? u[r + 1][c] : bh[c];
                float lf = (c > 0)       ? orow[c - 1] : lsh[r];
                float rt = (c < PTX - 1) ? orow[c + 1] : rsh[r];
                float s  = (up + dn) + (lf + rt);
                float od = orow[c];
                float tq = __builtin_fmaf(0.25f, s, -od);
                u[r][c]  = __builtin_fmaf(cf[r][c], tq, od);
            }
#pragma unroll
            for (int c = 0; c < PTX; ++c) prow[c] = orow[c];
        }
    }

    // ---- store center 112x48: threads tr in [1,15), tc in [2,14) ----
    const bool inner = (tr >= 1) & (tr < 15) & (tc >= 2) & (tc < 14);
    if (!FINAL) {
        if (inner) {
            unsigned short* og = uout + slab;
            int gcol = ox + C0 - HALO;
#pragma unroll
            for (int r = 0; r < PTY; ++r) {
                int grow = oy + R0 + r - HALO;
                unsigned a = bf16_st(u[r][0]) | ((unsigned)bf16_st(u[r][1]) << 16);
                unsigned d = bf16_st(u[r][2]) | ((unsigned)bf16_st(u[r][3]) << 16);
                *(uint2*)(og + grow * NN + gcol) = make_uint2(a, d);
            }
        }
    } else {
        if (inner) {
            float* og = fout + slab;
            const unsigned short* pg = pre + slab;
            float rs  = 0.25f / (1.0f + expf(-logit[0]));
            float ym  = y_mean[0];
            float inv = 1.0f / (y_std[0] + EPS_F);
            int gcol = ox + C0 - HALO;
#pragma unroll
            for (int r = 0; r < PTY; ++r) {
                int grow = oy + R0 + r - HALO;
                uint2 pv = *(const uint2*)(pg + grow * NN + gcol);
                unsigned pwv[2] = {pv.x, pv.y};
                float4 o;
                float* op = &o.x;
#pragma unroll
                for (int c = 0; c < PTX; ++c) {
                    float e = (u[r][c] - ym) * inv;
                    float p = bf16_ld((unsigned short)((pwv[c >> 1] >> ((c & 1) * 16)) & 0xFFFFu));
                    op[c] = __builtin_fmaf(rs, p, e);
                }
                *(float4*)(og + grow * NN + gcol) = o;
            }
        }
    }
}

// ---------------------------------------------------------------------------
extern "C" void kernel_launch(void* const* d_in, const int* in_sizes, int n_in,
                              void* d_out, int out_size, void* d_ws, size_t ws_size,
                              hipStream_t stream)
{
    const float* x_mix  = (const float*)d_in[0];
    const float* w_back = (const float*)d_in[1];
    const float* b_back = (const float*)d_in[2];
    const float* logit  = (const float*)d_in[3];
    const float* y_mean = (const float*)d_in[4];
    const float* y_std  = (const float*)d_in[5];

    float* out = (float*)d_out;

    // Workspace: [GUARD][u_a 2B][cmask 1B][u_b 2B][pre 2B] — halo reads may
    // stray up to ~8.3 KB past either end of u_a/cmask/u_b; every such access
    // lands in an adjacent defined region or the guard (finite bf16 values),
    // and garbage cannot cross the frozen global-edge rows/cols.
    char* ws = (char*)d_ws;
    unsigned short* u_a   = (unsigned short*)(ws + GUARD);
    unsigned char*  cmask = (unsigned char*) (ws + GUARD + (size_t)TOTAL * 2);
    unsigned short* u_b   = (unsigned short*)(ws + GUARD + (size_t)TOTAL * 3);
    unsigned short* pre   = (unsigned short*)(ws + GUARD + (size_t)TOTAL * 5);

    init_kernel<<<TOTAL / 4 / 256, 256, 0, stream>>>(
        (const float4*)x_mix, u_a, cmask, pre, w_back, b_back);

    // 50 iters = 6 launches x 8 + 1 launch x 2 (fused epilogue).
    // Chain: a->b, b->a, a->b, b->a, a->b, b->a, then FINAL a->out.
    dim3 sgrid((NN + OUT_W - 1) / OUT_W, (NN + OUT_H - 1) / OUT_H, BB);  // 11x5x16
    stencil_kernel<8, false><<<sgrid, 256, 0, stream>>>(u_a, u_b, out, cmask,
        pre, logit, y_mean, y_std);
    stencil_kernel<8, false><<<sgrid, 256, 0, stream>>>(u_b, u_a, out, cmask,
        pre, logit, y_mean, y_std);
    stencil_kernel<8, false><<<sgrid, 256, 0, stream>>>(u_a, u_b, out, cmask,
        pre, logit, y_mean, y_std);
    stencil_kernel<8, false><<<sgrid, 256, 0, stream>>>(u_b, u_a, out, cmask,
        pre, logit, y_mean, y_std);
    stencil_kernel<8, false><<<sgrid, 256, 0, stream>>>(u_a, u_b, out, cmask,
        pre, logit, y_mean, y_std);
    stencil_kernel<8, false><<<sgrid, 256, 0, stream>>>(u_b, u_a, out, cmask,
        pre, logit, y_mean, y_std);
    stencil_kernel<2, true><<<sgrid, 256, 0, stream>>>(u_a, u_b, out, cmask,
        pre, logit, y_mean, y_std);
}